// Round 18
// baseline (143.943 us; speedup 1.0000x reference)
//
#include <hip/hip_runtime.h>
#include <hip/hip_bf16.h>
#include <stdint.h>

// ---------------------------------------------------------------------------
// Per-type MLP dispatch (ElemwiseModels): out[n] = MLP_{elems[n]}(desc[n])
//   L1: h1 = tanh(x @ W1[t] + b1[t])     x:256 -> 256
//   L2: h2 = tanh(h1 @ W2[t] + b2[t])    256 -> 256
//   L3: out = h2 . W3[t] + b3[t]         256 -> 1
// r18: r16's 16-wave (4 waves/SIMD) structure WITHOUT weight hoisting —
// weight frags load per-ks from L2-resident w1s/w2s (r7-style). Register
// footprint ~100 < 128 budget -> no spill (r16's sole failure mode), and
// the 4-waves/SIMD TLP gets a clean test.
//   - persistent type-pinned blocks (grid 256 = 64 x 4 types), 1024 thr
//   - x staged fp32 by zero-VGPR global_load_lds DMA, double-buffered,
//     source-XOR-swizzled; fp32->bf16 folded into L1 frag read
//   - fragment layouts + L3 mapping: r7/r11/r14/r16-validated
// ---------------------------------------------------------------------------

typedef __attribute__((ext_vector_type(8))) short short8;   // 8 x bf16 frag
typedef __attribute__((ext_vector_type(4))) float f32x4;    // MFMA acc

#define NPB 256          // partition blocks
#define NTY 4            // types
#define XBUF_BYTES 69632 // 4 groups * 16 chunks * 1088

typedef __attribute__((address_space(3))) void lds_void;
typedef __attribute__((address_space(1))) const void glb_void;

__device__ __forceinline__ unsigned short f2bf(float f) {
    union { float f; uint32_t u; } v; v.f = f;
    uint32_t u = v.u;
    uint32_t r = (u + 0x7FFFu + ((u >> 16) & 1u)) >> 16;   // RN-even
    return (unsigned short)r;
}
__device__ __forceinline__ float fast_tanh(float x) {
    x = fminf(fmaxf(x, -10.0f), 10.0f);
    float e = __expf(2.0f * x);
    return (e - 1.0f) * __builtin_amdgcn_rcpf(e + 1.0f);
}

// ---------------- ws layout -------------------------------------------------
// hdr   (32 ints @ 0):      [0..3] counts, [8..11] base, [12..15] tilebase, [16] total tiles
// counts(4*NPB ints @128);  cursor(4*NPB ints);  sorted(n ints);  w1s/w2s (bf16)
// ---------------------------------------------------------------------------

__global__ void count_k(const int* __restrict__ elems, int n, int chunk,
                        int* __restrict__ counts) {
    __shared__ int h[NTY];
    if (threadIdx.x < NTY) h[threadIdx.x] = 0;
    __syncthreads();
    const int start = blockIdx.x * chunk;
    const int end   = min(start + chunk, n);
    for (int i = start + threadIdx.x; i < end; i += blockDim.x)
        atomicAdd(&h[elems[i]], 1);
    __syncthreads();
    if (threadIdx.x < NTY) counts[threadIdx.x * NPB + blockIdx.x] = h[threadIdx.x];
}

__global__ void prefix_k(const int* __restrict__ counts,
                         int* __restrict__ cursor, int* __restrict__ hdr) {
    __shared__ int tot[NTY];
    const int t = threadIdx.x;
    if (t < NTY) {
        int s = 0;
        for (int b = 0; b < NPB; ++b) s += counts[t * NPB + b];
        tot[t] = s;
    }
    __syncthreads();
    if (t == 0) {
        int b = 0, tb = 0;
        for (int ty = 0; ty < NTY; ++ty) {
            hdr[ty]      = tot[ty];
            hdr[8 + ty]  = b;
            hdr[12 + ty] = tb;
            b  += tot[ty];
            tb += (tot[ty] + 63) >> 6;
        }
        hdr[16] = tb;
    }
    __syncthreads();
    if (t < NTY) {
        int run = hdr[8 + t];
        for (int b = 0; b < NPB; ++b) {
            cursor[t * NPB + b] = run;
            run += counts[t * NPB + b];
        }
    }
}

__global__ void scatter_k(const int* __restrict__ elems, int n, int chunk,
                          const int* __restrict__ cursor, int* __restrict__ sorted) {
    __shared__ int cur[NTY];
    if (threadIdx.x < NTY) cur[threadIdx.x] = cursor[threadIdx.x * NPB + blockIdx.x];
    __syncthreads();
    const int start = blockIdx.x * chunk;
    const int end   = min(start + chunk, n);
    for (int i = start + threadIdx.x; i < end; i += blockDim.x) {
        int ty  = elems[i];
        int pos = atomicAdd(&cur[ty], 1);   // LDS atomic: block-local
        sorted[pos] = i;
    }
}

// Pre-swizzle W1,W2 (fp32 [t][din][dout]) into bf16 MFMA-frag order:
// frag(t,tile,ks): 64 lanes x 16B contiguous; lane l elem j =
//   W[t][ks*32 + (l>>4)*8 + j][tile*16 + (l&15)]
__global__ void wconv_k(const float* __restrict__ W1, const float* __restrict__ W2,
                        unsigned short* __restrict__ w1s, unsigned short* __restrict__ w2s) {
    int gid  = blockIdx.x * blockDim.x + threadIdx.x;   // 0..65535
    int lane = gid & 63;
    int ks   = (gid >> 6) & 7;
    int tile = (gid >> 9) & 15;
    int t    = (gid >> 13) & 3;
    int layer = gid >> 15;
    const float* W = layer ? W2 : W1;
    unsigned short* o = layer ? w2s : w1s;
    int dbase = ks * 32 + ((lane >> 4) << 3);
    int col   = tile * 16 + (lane & 15);
    unsigned short v[8];
#pragma unroll
    for (int j = 0; j < 8; ++j)
        v[j] = f2bf(W[(size_t)t * 65536 + (size_t)(dbase + j) * 256 + col]);
    unsigned short* dst = o + ((size_t)(t * 16 + tile) * 8 + ks) * 512 + lane * 8;
    *(short8*)dst = *(short8*)v;
}

// read bf16 B-frag (8 k-values) for atom-row a, fp32 byte offset c0 in row,
// from the DMA-staged swizzled x buffer; converts fp32->bf16 on the fly.
__device__ __forceinline__ short8 read_xfrag(const char* cb, int a, int c0) {
    const int swz = (a & 7) << 4;
    const int cs0 = c0 ^ swz;
    const int cs1 = (c0 + 16) ^ swz;
    const int ab  = (a >> 4) * 17408 + (a & 15) * 64;
    const float4 f0 = *(const float4*)(cb + ab + (cs0 >> 6) * 1088 + (cs0 & 0x30));
    const float4 f1 = *(const float4*)(cb + ab + (cs1 >> 6) * 1088 + (cs1 & 0x30));
    union { short8 s; __hip_bfloat162 h[4]; } u;
    u.h[0] = __float22bfloat162_rn(make_float2(f0.x, f0.y));
    u.h[1] = __float22bfloat162_rn(make_float2(f0.z, f0.w));
    u.h[2] = __float22bfloat162_rn(make_float2(f1.x, f1.y));
    u.h[3] = __float22bfloat162_rn(make_float2(f1.z, f1.w));
    return u.s;
}

// ---------------------------------------------------------------------------
// Persistent type-pinned main kernel: 256 blocks (64 per type), 1024 threads
// (16 waves = 4 waves/SIMD). Wave w owns h-tile w (L1) and kout-tile w (L2);
// weight frags load per-ks from L2-resident w1s/w2s (no hoisting -> no spill).
// LDS: 2 x 68KB DMA x-buffers (h1 bf16 reuses retiring buffer) + part[16][64].
// ---------------------------------------------------------------------------
__global__ __launch_bounds__(1024, 1) void mlp_k(
    const float* __restrict__ desc,
    const float* __restrict__ b1g,
    const float* __restrict__ b2g,
    const float* __restrict__ W3,
    const float* __restrict__ b3,
    const int* __restrict__ hdr,
    const int* __restrict__ sorted,
    const unsigned short* __restrict__ w1s,
    const unsigned short* __restrict__ w2s,
    float* __restrict__ out)
{
    __shared__ __align__(16) char buf[2][XBUF_BYTES];
    __shared__ float part[16][64];

    const int tid  = threadIdx.x;
    const int lane = tid & 63;
    const int w    = tid >> 6;        // wave 0..15
    const int g    = lane >> 4;       // k-group 0..3 (frag reads)
    const int a16  = lane & 15;
    // staging ids: wave stages group (w&3), chunks (w>>2)*4 .. +3
    const int sa   = lane >> 2;       // atom within group 0..15
    const int qq   = lane & 3;        // 16B quarter of 64B chunk
    const int gw   = w & 3;           // staged group
    const int ch   = w >> 2;          // chunk quarter 0..3
    const int sswz = (sa & 7) << 4;

    const int t     = blockIdx.x >> 6;     // type (block pinned)
    const int bslot = blockIdx.x & 63;
    const int cnt   = hdr[t];
    const int base  = hdr[8 + t];
    const int ntile = (cnt + 63) >> 6;
    if (bslot >= ntile) return;

#define STAGE(J, BP)                                                          \
    {                                                                         \
        const int gg_  = (J) * 64 + gw * 16 + sa;                             \
        const int idx_ = (gg_ < cnt) ? sorted[base + gg_] : 0;                \
        const float* rowp_ = desc + (size_t)idx_ * 256;                       \
        _Pragma("unroll")                                                     \
        for (int i_ = 0; i_ < 4; ++i_) {                                      \
            const int c_ = ch * 4 + i_;                                       \
            const float* src_ = rowp_ + (((c_ * 64 + qq * 16) ^ sswz) >> 2);  \
            char* dst_ = (BP) + gw * 17408 + c_ * 1088;                       \
            __builtin_amdgcn_global_load_lds((glb_void*)src_,                 \
                                             (lds_void*)dst_, 16, 0, 0);      \
        }                                                                     \
    }

    // ---- prologue: DMA first tile
    int j = bslot;
    STAGE(j, buf[0]);

    const unsigned short* w1t = w1s + (size_t)t * (16 * 8 * 512);
    const unsigned short* w2t = w2s + (size_t)t * (16 * 8 * 512);
    const float4 bq = *(const float4*)(b1g + t * 256 + w * 16 + g * 4);
    const int kout  = w * 16 + a16;
    const float w3r = W3[t * 256 + kout];
    const float b2r = b2g[t * 256 + kout];
    const float b3v = b3[t];

    for (int k = 0;; ++k) {
        const int cur = k & 1;
        const int jn  = j + 64;
        const bool has_next = (jn < ntile);

        // buf[cur]'s DMA (issued one tile ago) must be complete everywhere
        asm volatile("s_waitcnt vmcnt(0)" ::: "memory");
        __syncthreads();

        // issue next tile's DMA into the other buffer
        if (has_next) STAGE(jn, buf[cur ^ 1]);

        const char* cb = buf[cur];

        // ---- L1: C1[h][atom]; wave owns h-tile w
        f32x4 acc[4];
#pragma unroll
        for (int nt = 0; nt < 4; ++nt)
            acc[nt] = (f32x4){0.f, 0.f, 0.f, 0.f};

#pragma unroll
        for (int ks = 0; ks < 8; ++ks) {
            const short8 af = *(const short8*)(w1t + ((size_t)(w * 8 + ks)) * 512 + lane * 8);
            short8 bh[4];
            const int c0 = ks * 128 + g * 32;   // fp32 byte offset in row
#pragma unroll
            for (int nt = 0; nt < 4; ++nt)
                bh[nt] = read_xfrag(cb, nt * 16 + a16, c0);
#pragma unroll
            for (int nt = 0; nt < 4; ++nt)
                acc[nt] = __builtin_amdgcn_mfma_f32_16x16x32_bf16(af, bh[nt], acc[nt], 0, 0, 0);
        }
        __syncthreads();   // all waves done reading x from buf[cur]

        // ---- ep1: bias + tanh -> bf16 h1 into buf[cur][0..32K)
        {
            char* hb = buf[cur];
            const int h0 = w * 16 + g * 4;
#pragma unroll
            for (int nt = 0; nt < 4; ++nt) {
                const int atom = nt * 16 + a16;
                unsigned short h4[4];
                h4[0] = f2bf(fast_tanh(acc[nt][0] + bq.x));
                h4[1] = f2bf(fast_tanh(acc[nt][1] + bq.y));
                h4[2] = f2bf(fast_tanh(acc[nt][2] + bq.z));
                h4[3] = f2bf(fast_tanh(acc[nt][3] + bq.w));
                const int off = atom * 512 + ((h0 * 2) ^ ((atom & 7) << 4));
                *(ushort4*)(hb + off) = *(ushort4*)h4;
            }
        }
        __syncthreads();   // h1 fully written

        // ---- L2: C2[atom][kout]; wave owns kout-tile w
        f32x4 acc2[4];
#pragma unroll
        for (int mt = 0; mt < 4; ++mt)
            acc2[mt] = (f32x4){0.f, 0.f, 0.f, 0.f};

#pragma unroll
        for (int ks = 0; ks < 8; ++ks) {
            const short8 bw = *(const short8*)(w2t + ((size_t)(w * 8 + ks)) * 512 + lane * 8);
            short8 ah[4];
            const int colb = ks * 64 + g * 16;
#pragma unroll
            for (int mt = 0; mt < 4; ++mt) {
                const int row = mt * 16 + a16;
                const int off = row * 512 + (colb ^ ((row & 7) << 4));
                ah[mt] = *(const short8*)(cb + off);
            }
#pragma unroll
            for (int mt = 0; mt < 4; ++mt)
                acc2[mt] = __builtin_amdgcn_mfma_f32_16x16x32_bf16(ah[mt], bw, acc2[mt], 0, 0, 0);
        }

        // ---- L3: acc2[mt][r] = C2[atom=mt*16+g*4+r][kout=w*16+a16]
        float psum[4][4];
#pragma unroll
        for (int mt = 0; mt < 4; ++mt)
#pragma unroll
            for (int r = 0; r < 4; ++r)
                psum[mt][r] = fast_tanh(acc2[mt][r] + b2r) * w3r;

#pragma unroll
        for (int m = 1; m <= 8; m <<= 1)
#pragma unroll
            for (int mt = 0; mt < 4; ++mt)
#pragma unroll
                for (int r = 0; r < 4; ++r)
                    psum[mt][r] += __shfl_xor(psum[mt][r], m, 64);

        if (a16 == 0) {
#pragma unroll
            for (int mt = 0; mt < 4; ++mt)
#pragma unroll
                for (int r = 0; r < 4; ++r)
                    part[w][mt * 16 + g * 4 + r] = psum[mt][r];
        }
        __syncthreads();   // partials ready

        if (tid < 64) {
            const int gg = j * 64 + tid;
            if (gg < cnt) {
                float v = b3v;
#pragma unroll
                for (int ww = 0; ww < 16; ++ww) v += part[ww][tid];
                out[sorted[base + gg]] = v;
            }
        }

        if (!has_next) break;
        j = jn;
    }
#undef STAGE
}

extern "C" void kernel_launch(void* const* d_in, const int* in_sizes, int n_in,
                              void* d_out, int out_size, void* d_ws, size_t ws_size,
                              hipStream_t stream) {
    const float* desc = (const float*)d_in[0];
    const int*   elems = (const int*)d_in[1];
    const float* W1 = (const float*)d_in[2];
    const float* b1 = (const float*)d_in[3];
    const float* W2 = (const float*)d_in[4];
    const float* b2 = (const float*)d_in[5];
    const float* W3 = (const float*)d_in[6];
    const float* b3 = (const float*)d_in[7];
    float* out = (float*)d_out;
    const int n = in_sizes[1];   // N_ATOMS

    char* ws = (char*)d_ws;
    int* hdr    = (int*)ws;                       // 32 ints
    int* counts = (int*)(ws + 128);               // 4*NPB ints
    int* cursor = (int*)(ws + 128 + 4 * NPB * 4); // 4*NPB ints
    int* sorted = (int*)(ws + 128 + 8 * NPB * 4);
    unsigned short* w1s = (unsigned short*)((char*)sorted + (size_t)n * 4);
    unsigned short* w2s = w1s + (size_t)4 * 16 * 8 * 512;

    const int chunk = (n + NPB - 1) / NPB;

    count_k<<<NPB, 256, 0, stream>>>(elems, n, chunk, counts);
    prefix_k<<<1, 64, 0, stream>>>(counts, cursor, hdr);
    scatter_k<<<NPB, 256, 0, stream>>>(elems, n, chunk, cursor, sorted);
    wconv_k<<<256, 256, 0, stream>>>(W1, W2, w1s, w2s);

    mlp_k<<<NTY * 64, 1024, 0, stream>>>(desc, b1, b2, W3, b3,
                                         hdr, sorted, w1s, w2s, out);
}

// Round 19
// 106.525 us; speedup vs baseline: 1.3513x; 1.3513x over previous
//
#include <hip/hip_runtime.h>
#include <hip/hip_bf16.h>
#include <stdint.h>

// ---------------------------------------------------------------------------
// Per-type MLP dispatch (ElemwiseModels): out[n] = MLP_{elems[n]}(desc[n])
//   L1: h1 = tanh(x @ W1[t] + b1[t])     x:256 -> 256
//   L2: h2 = tanh(h1 @ W2[t] + b2[t])    256 -> 256
//   L3: out = h2 . W3[t] + b3[t]         256 -> 1
// r19: SPLIT at the h1 boundary into two simple high-occupancy kernels:
//   mlp1_k: stage x (bf16, LDS 32KB) -> L1 block-coop MFMA -> tanh ->
//           write h1 bf16 rows to workspace (coalesced)
//   mlp2_k: DMA-stage h1 (source-XOR-swizzled, r14 trick) -> L2 -> L3 -> out
// Each kernel: short phase chain, 32KB LDS, ~120 VGPR -> 3-4 blocks/CU of
// INDEPENDENT work (the TLP the fused structure could never afford without
// spilling — r15-r18 evidence). h1 round trip = 134MB, mostly L3-resident.
// Fragment layouts / L3 mapping: r7/r11/r14-validated.
// ---------------------------------------------------------------------------

typedef __attribute__((ext_vector_type(8))) short short8;   // 8 x bf16 frag
typedef __attribute__((ext_vector_type(4))) float f32x4;    // MFMA acc

#define NPB 256          // partition blocks
#define NTY 4            // types

typedef __attribute__((address_space(3))) void lds_void;
typedef __attribute__((address_space(1))) const void glb_void;

__device__ __forceinline__ unsigned short f2bf(float f) {
    union { float f; uint32_t u; } v; v.f = f;
    uint32_t u = v.u;
    uint32_t r = (u + 0x7FFFu + ((u >> 16) & 1u)) >> 16;   // RN-even
    return (unsigned short)r;
}
__device__ __forceinline__ float fast_tanh(float x) {
    x = fminf(fmaxf(x, -10.0f), 10.0f);
    float e = __expf(2.0f * x);
    return (e - 1.0f) * __builtin_amdgcn_rcpf(e + 1.0f);
}

// ---------------- ws layout -------------------------------------------------
// hdr(32 int @0); counts(4*NPB @128); cursor(4*NPB); sorted(n int);
// w1s(1MB); w2s(1MB); h1(n*512B)  -> total ~70 MB
// ---------------------------------------------------------------------------

__global__ void count_k(const int* __restrict__ elems, int n, int chunk,
                        int* __restrict__ counts) {
    __shared__ int h[NTY];
    if (threadIdx.x < NTY) h[threadIdx.x] = 0;
    __syncthreads();
    const int start = blockIdx.x * chunk;
    const int end   = min(start + chunk, n);
    for (int i = start + threadIdx.x; i < end; i += blockDim.x)
        atomicAdd(&h[elems[i]], 1);
    __syncthreads();
    if (threadIdx.x < NTY) counts[threadIdx.x * NPB + blockIdx.x] = h[threadIdx.x];
}

__global__ void prefix_k(const int* __restrict__ counts,
                         int* __restrict__ cursor, int* __restrict__ hdr) {
    __shared__ int tot[NTY];
    const int t = threadIdx.x;
    if (t < NTY) {
        int s = 0;
        for (int b = 0; b < NPB; ++b) s += counts[t * NPB + b];
        tot[t] = s;
    }
    __syncthreads();
    if (t == 0) {
        int b = 0, tb = 0;
        for (int ty = 0; ty < NTY; ++ty) {
            hdr[ty]      = tot[ty];
            hdr[8 + ty]  = b;
            hdr[12 + ty] = tb;
            b  += tot[ty];
            tb += (tot[ty] + 63) >> 6;
        }
        hdr[16] = tb;
    }
    __syncthreads();
    if (t < NTY) {
        int run = hdr[8 + t];
        for (int b = 0; b < NPB; ++b) {
            cursor[t * NPB + b] = run;
            run += counts[t * NPB + b];
        }
    }
}

__global__ void scatter_k(const int* __restrict__ elems, int n, int chunk,
                          const int* __restrict__ cursor, int* __restrict__ sorted) {
    __shared__ int cur[NTY];
    if (threadIdx.x < NTY) cur[threadIdx.x] = cursor[threadIdx.x * NPB + blockIdx.x];
    __syncthreads();
    const int start = blockIdx.x * chunk;
    const int end   = min(start + chunk, n);
    for (int i = start + threadIdx.x; i < end; i += blockDim.x) {
        int ty  = elems[i];
        int pos = atomicAdd(&cur[ty], 1);   // LDS atomic: block-local
        sorted[pos] = i;
    }
}

// Pre-swizzle W1,W2 (fp32 [t][din][dout]) into bf16 MFMA-frag order:
// frag(t,tile,ks): 64 lanes x 16B contiguous; lane l elem j =
//   W[t][ks*32 + (l>>4)*8 + j][tile*16 + (l&15)]
__global__ void wconv_k(const float* __restrict__ W1, const float* __restrict__ W2,
                        unsigned short* __restrict__ w1s, unsigned short* __restrict__ w2s) {
    int gid  = blockIdx.x * blockDim.x + threadIdx.x;   // 0..65535
    int lane = gid & 63;
    int ks   = (gid >> 6) & 7;
    int tile = (gid >> 9) & 15;
    int t    = (gid >> 13) & 3;
    int layer = gid >> 15;
    const float* W = layer ? W2 : W1;
    unsigned short* o = layer ? w2s : w1s;
    int dbase = ks * 32 + ((lane >> 4) << 3);
    int col   = tile * 16 + (lane & 15);
    unsigned short v[8];
#pragma unroll
    for (int j = 0; j < 8; ++j)
        v[j] = f2bf(W[(size_t)t * 65536 + (size_t)(dbase + j) * 256 + col]);
    unsigned short* dst = o + ((size_t)(t * 16 + tile) * 8 + ks) * 512 + lane * 8;
    *(short8*)dst = *(short8*)v;
}

#define TILEINFO(TL, T, CNT, BASE, AST)                          \
    {                                                            \
        T = 3;                                                   \
        if      ((TL) < hdr[13]) T = 0;                          \
        else if ((TL) < hdr[14]) T = 1;                          \
        else if ((TL) < hdr[15]) T = 2;                          \
        CNT = hdr[T]; BASE = hdr[8 + T];                         \
        AST = ((TL) - hdr[12 + T]) * 64;                         \
    }

// ---------------------------------------------------------------------------
// mlp1_k: one block = 64 atoms. Stage x bf16 -> L1 MFMA -> tanh -> h1 to ws.
// LDS 32KB -> 3-4 blocks/CU.
// ---------------------------------------------------------------------------
__global__ __launch_bounds__(256, 2) void mlp1_k(
    const float* __restrict__ desc,
    const float* __restrict__ b1g,
    const int* __restrict__ hdr,
    const int* __restrict__ sorted,
    const unsigned short* __restrict__ w1s,
    unsigned short* __restrict__ h1g)
{
    __shared__ __align__(16) char buf[32768];   // x bf16 [64][512B] swz; then h1

    const int tid  = threadIdx.x;
    const int lane = tid & 63;
    const int w    = tid >> 6;

    const int b = blockIdx.x;
    if (b >= hdr[16]) return;
    int t, cnt, base, astart;
    TILEINFO(b, t, cnt, base, astart);

    // ---- stage x: 4 threads per atom slot, plain bf16, swizzled
    {
        const int slot = tid >> 2;
        const int q4   = tid & 3;
        const int gg   = astart + slot;
        const int idx  = (gg < cnt) ? sorted[base + gg] : 0;
        const float4* row = (const float4*)(desc + (size_t)idx * 256);
#pragma unroll
        for (int i = 0; i < 16; ++i) {
            const int f = q4 + i * 4;
            const float4 v = row[f];
            unsigned short h4[4];
            h4[0] = f2bf(v.x); h4[1] = f2bf(v.y);
            h4[2] = f2bf(v.z); h4[3] = f2bf(v.w);
            const int off = slot * 512 + ((f * 8) ^ ((slot & 7) << 4));
            *(ushort4*)(buf + off) = *(ushort4*)h4;
        }
    }
    __syncthreads();

    const unsigned short* w1t = w1s + (size_t)t * (16 * 8 * 512);

    // ---- L1: C1[h][atom]; wave owns h-tiles w*4..w*4+3
    f32x4 acc[4][4];
#pragma unroll
    for (int q = 0; q < 4; ++q)
#pragma unroll
        for (int nt = 0; nt < 4; ++nt)
            acc[q][nt] = (f32x4){0.f, 0.f, 0.f, 0.f};

#pragma unroll
    for (int ks = 0; ks < 8; ++ks) {
        short8 af[4];
#pragma unroll
        for (int q = 0; q < 4; ++q)
            af[q] = *(const short8*)(w1t + ((size_t)((w * 4 + q) * 8 + ks)) * 512 + lane * 8);
        short8 bh[4];
        const int colb = ks * 64 + ((lane >> 4) << 4);
#pragma unroll
        for (int nt = 0; nt < 4; ++nt) {
            const int row = nt * 16 + (lane & 15);
            const int off = row * 512 + (colb ^ ((row & 7) << 4));
            bh[nt] = *(const short8*)(buf + off);
        }
#pragma unroll
        for (int q = 0; q < 4; ++q)
#pragma unroll
            for (int nt = 0; nt < 4; ++nt)
                acc[q][nt] = __builtin_amdgcn_mfma_f32_16x16x32_bf16(af[q], bh[nt], acc[q][nt], 0, 0, 0);
    }
    __syncthreads();   // x fully consumed

    // ---- ep1: bias + tanh -> bf16 h1 into buf (same XOR layout)
#pragma unroll
    for (int q = 0; q < 4; ++q) {
        const int h0 = (w * 4 + q) * 16 + ((lane >> 4) << 2);
        const float4 bb = *(const float4*)(b1g + t * 256 + h0);
#pragma unroll
        for (int nt = 0; nt < 4; ++nt) {
            const int atom = nt * 16 + (lane & 15);
            unsigned short h4[4];
            h4[0] = f2bf(fast_tanh(acc[q][nt][0] + bb.x));
            h4[1] = f2bf(fast_tanh(acc[q][nt][1] + bb.y));
            h4[2] = f2bf(fast_tanh(acc[q][nt][2] + bb.z));
            h4[3] = f2bf(fast_tanh(acc[q][nt][3] + bb.w));
            const int off = atom * 512 + ((h0 * 2) ^ ((atom & 7) << 4));
            *(ushort4*)(buf + off) = *(ushort4*)h4;
        }
    }
    __syncthreads();   // h1 fully written

    // ---- copy h1 LDS -> ws, un-swizzled rows, coalesced (32 lanes per row)
    {
        const int p  = tid & 31;          // 16B piece within row
        const int a0 = tid >> 5;          // 0..7
#pragma unroll
        for (int i = 0; i < 8; ++i) {
            const int atom = a0 + i * 8;
            const int gg   = astart + atom;
            const uint4 v = *(const uint4*)(buf + atom * 512 + ((p * 16) ^ ((atom & 7) << 4)));
            if (gg < cnt)
                *(uint4*)((char*)h1g + (size_t)(base + gg) * 512 + p * 16) = v;
        }
    }
}

// ---------------------------------------------------------------------------
// mlp2_k: one block = 64 atoms. DMA-stage h1 (pre-swizzled source) -> L2
// MFMA -> L3 dot/reduce -> out. LDS 33KB -> 3-4 blocks/CU.
// ---------------------------------------------------------------------------
__global__ __launch_bounds__(256, 2) void mlp2_k(
    const float* __restrict__ b2g,
    const float* __restrict__ W3,
    const float* __restrict__ b3,
    const int* __restrict__ hdr,
    const int* __restrict__ sorted,
    const unsigned short* __restrict__ w2s,
    const unsigned short* __restrict__ h1g,
    float* __restrict__ out)
{
    __shared__ __align__(16) char buf[32768];   // h1 bf16 [64][512B] swz content
    __shared__ float part[4][64];

    const int tid  = threadIdx.x;
    const int lane = tid & 63;
    const int w    = tid >> 6;

    const int b = blockIdx.x;
    if (b >= hdr[16]) return;
    int t, cnt, base, astart;
    TILEINFO(b, t, cnt, base, astart);

    // ---- DMA-stage h1: wave w stages rows w*16..w*16+15; source pre-swizzled
#pragma unroll
    for (int i = 0; i < 8; ++i) {
        const int row = w * 16 + i * 2 + (lane >> 5);
        const int p   = lane & 31;
        const int gg  = astart + row;
        const size_t srow = (size_t)(base + ((gg < cnt) ? gg : 0));
        const char* src = (const char*)h1g + srow * 512 + ((p * 16) ^ ((row & 7) << 4));
        char* dst = buf + w * 8192 + i * 1024;   // wave-uniform base + lane*16
        __builtin_amdgcn_global_load_lds((glb_void*)src, (lds_void*)dst, 16, 0, 0);
    }
    asm volatile("s_waitcnt vmcnt(0)" ::: "memory");
    __syncthreads();

    const unsigned short* w2t = w2s + (size_t)t * (16 * 8 * 512);

    // ---- L2: C2[atom][kout]; wave owns kout-tiles w*4..w*4+3
    f32x4 acc2[4][4];
#pragma unroll
    for (int mt = 0; mt < 4; ++mt)
#pragma unroll
        for (int q = 0; q < 4; ++q)
            acc2[mt][q] = (f32x4){0.f, 0.f, 0.f, 0.f};

#pragma unroll
    for (int ks = 0; ks < 8; ++ks) {
        short8 bw[4];
#pragma unroll
        for (int q = 0; q < 4; ++q)
            bw[q] = *(const short8*)(w2t + ((size_t)((w * 4 + q) * 8 + ks)) * 512 + lane * 8);
        short8 ah[4];
        const int colb = ks * 64 + ((lane >> 4) << 4);
#pragma unroll
        for (int mt = 0; mt < 4; ++mt) {
            const int row = mt * 16 + (lane & 15);
            const int off = row * 512 + (colb ^ ((row & 7) << 4));
            ah[mt] = *(const short8*)(buf + off);
        }
#pragma unroll
        for (int mt = 0; mt < 4; ++mt)
#pragma unroll
            for (int q = 0; q < 4; ++q)
                acc2[mt][q] = __builtin_amdgcn_mfma_f32_16x16x32_bf16(ah[mt], bw[q], acc2[mt][q], 0, 0, 0);
    }

    // ---- L3: fp32 dot with W3 over this wave's 64 kout columns
    float psum[4][4];
#pragma unroll
    for (int mt = 0; mt < 4; ++mt)
#pragma unroll
        for (int r = 0; r < 4; ++r)
            psum[mt][r] = 0.f;

#pragma unroll
    for (int q = 0; q < 4; ++q) {
        const int kout = (w * 4 + q) * 16 + (lane & 15);
        const float w3v = W3[t * 256 + kout];
        const float b2v = b2g[t * 256 + kout];
#pragma unroll
        for (int mt = 0; mt < 4; ++mt)
#pragma unroll
            for (int r = 0; r < 4; ++r)
                psum[mt][r] += fast_tanh(acc2[mt][q][r] + b2v) * w3v;
    }
#pragma unroll
    for (int m = 1; m <= 8; m <<= 1)
#pragma unroll
        for (int mt = 0; mt < 4; ++mt)
#pragma unroll
            for (int r = 0; r < 4; ++r)
                psum[mt][r] += __shfl_xor(psum[mt][r], m, 64);

    if ((lane & 15) == 0) {
        const int gq = lane >> 4;
#pragma unroll
        for (int mt = 0; mt < 4; ++mt)
#pragma unroll
            for (int r = 0; r < 4; ++r)
                part[w][mt * 16 + gq * 4 + r] = psum[mt][r];
    }
    __syncthreads();

    if (tid < 64) {
        const int gg = astart + tid;
        if (gg < cnt) {
            float v = part[0][tid] + part[1][tid] + part[2][tid] + part[3][tid] + b3[t];
            out[sorted[base + gg]] = v;
        }
    }
}

extern "C" void kernel_launch(void* const* d_in, const int* in_sizes, int n_in,
                              void* d_out, int out_size, void* d_ws, size_t ws_size,
                              hipStream_t stream) {
    const float* desc = (const float*)d_in[0];
    const int*   elems = (const int*)d_in[1];
    const float* W1 = (const float*)d_in[2];
    const float* b1 = (const float*)d_in[3];
    const float* W2 = (const float*)d_in[4];
    const float* b2 = (const float*)d_in[5];
    const float* W3 = (const float*)d_in[6];
    const float* b3 = (const float*)d_in[7];
    float* out = (float*)d_out;
    const int n = in_sizes[1];   // N_ATOMS

    char* ws = (char*)d_ws;
    int* hdr    = (int*)ws;                       // 32 ints
    int* counts = (int*)(ws + 128);               // 4*NPB ints
    int* cursor = (int*)(ws + 128 + 4 * NPB * 4); // 4*NPB ints
    int* sorted = (int*)(ws + 128 + 8 * NPB * 4);
    unsigned short* w1s = (unsigned short*)((char*)sorted + (size_t)n * 4);
    unsigned short* w2s = w1s + (size_t)4 * 16 * 8 * 512;
    unsigned short* h1g = w2s + (size_t)4 * 16 * 8 * 512;   // n*512 bytes

    const int chunk = (n + NPB - 1) / NPB;

    count_k<<<NPB, 256, 0, stream>>>(elems, n, chunk, counts);
    prefix_k<<<1, 64, 0, stream>>>(counts, cursor, hdr);
    scatter_k<<<NPB, 256, 0, stream>>>(elems, n, chunk, cursor, sorted);
    wconv_k<<<256, 256, 0, stream>>>(W1, W2, w1s, w2s);

    const int maxtiles = (n >> 6) + 4;
    mlp1_k<<<maxtiles, 256, 0, stream>>>(desc, b1, hdr, sorted, w1s, h1g);
    mlp2_k<<<maxtiles, 256, 0, stream>>>(b2, W3, b3, hdr, sorted, w2s, h1g, out);
}